// Round 1
// baseline (639.270 us; speedup 1.0000x reference)
//
#include <hip/hip_runtime.h>
#include <hip/hip_bf16.h>
#include <cstdint>
#include <cstddef>

#define E_EDGES 320000
#define NN 10000
#define NRELS 40
#define NB 30
#define HID 100
#define NHTOT (NN*HID)   // 1,000,000

// ---------------------------------------------------------------- counting
__global__ void k_count(const int* __restrict__ dst, const int* __restrict__ et,
                        int* __restrict__ cnt_nr, int* __restrict__ deg) {
  int e = blockIdx.x * blockDim.x + threadIdx.x;
  if (e >= E_EDGES) return;
  int d = dst[e], r = et[e];
  atomicAdd(&cnt_nr[d * NRELS + r], 1);
  atomicAdd(&deg[d], 1);
}

// single-block exclusive scan of deg[NN] -> rowptr[NN+1]
__global__ void k_scan(const int* __restrict__ deg, int* __restrict__ rowptr) {
  __shared__ int ssum[256];
  int t = threadIdx.x;
  const int per = (NN + 255) / 256;  // 40
  int base = t * per;
  int s = 0;
  for (int k = 0; k < per; ++k) { int i = base + k; if (i < NN) s += deg[i]; }
  ssum[t] = s; __syncthreads();
  for (int off = 1; off < 256; off <<= 1) {
    int v = (t >= off) ? ssum[t - off] : 0;
    __syncthreads();
    ssum[t] += v;
    __syncthreads();
  }
  int pre = (t == 0) ? 0 : ssum[t - 1];
  for (int k = 0; k < per; ++k) {
    int i = base + k;
    if (i < NN) { rowptr[i] = pre; pre += deg[i]; }
  }
  if (t == 255) rowptr[NN] = ssum[255];
}

__global__ void k_bucket(const int* __restrict__ src, const int* __restrict__ dst,
                         const int* __restrict__ et, const int* __restrict__ rowptr,
                         int* __restrict__ fill, int* __restrict__ ebuf) {
  int e = blockIdx.x * blockDim.x + threadIdx.x;
  if (e >= E_EDGES) return;
  int d = dst[e];
  int pos = rowptr[d] + atomicAdd(&fill[d], 1);
  ebuf[pos] = (src[e] << 6) | et[e];   // src<16384, rel<64
}

// ---------------------------------------------------------------- basis combos
// W1 chunk: big[rr*NHTOT + i] = sum_b comp1[(r0+rr),b] * basis1[b, i]   (i = node*HID+c)
__global__ void k_w1(const float* __restrict__ comp1, const float* __restrict__ basis1,
                     float* __restrict__ big, int r0, int rc) {
  int i = blockIdx.x * 256 + threadIdx.x;
  if (i >= NHTOT) return;
  float v[NB];
#pragma unroll
  for (int b = 0; b < NB; ++b) v[b] = basis1[(size_t)b * NHTOT + i];
  for (int rr = 0; rr < rc; ++rr) {
    float a = 0.f;
#pragma unroll
    for (int b = 0; b < NB; ++b) a += comp1[(r0 + rr) * NB + b] * v[b];
    big[(size_t)rr * NHTOT + i] = a;
  }
}

// W2[r, d, c] = sum_b comp2[r,b] * basis2[b, d, c]   (all 40 rels, 1.6 MB)
__global__ void k_w2(const float* __restrict__ comp2, const float* __restrict__ basis2,
                     float* __restrict__ W2) {
  int i = blockIdx.x * 256 + threadIdx.x;
  if (i >= HID * HID) return;
  float v[NB];
#pragma unroll
  for (int b = 0; b < NB; ++b) v[b] = basis2[b * HID * HID + i];
  for (int r = 0; r < NRELS; ++r) {
    float a = 0.f;
#pragma unroll
    for (int b = 0; b < NB; ++b) a += comp2[r * NB + b] * v[b];
    W2[r * HID * HID + i] = a;
  }
}

// ---------------------------------------------------------------- conv1 aggregate
__global__ void k_agg1(const int* __restrict__ rowptr, const int* __restrict__ ebuf,
                       const int* __restrict__ cnt_nr, const float* __restrict__ big,
                       const float* __restrict__ root1, const float* __restrict__ bias1,
                       float* __restrict__ hacc, float* __restrict__ h,
                       int r0, int rc, int first, int last) {
  int n = blockIdx.x, t = threadIdx.x;
  int c1 = t + 64;                 // valid if < HID
  float a0 = 0.f, a1 = 0.f;
  int beg = rowptr[n], end = rowptr[n + 1];
  for (int j = beg; j < end; ++j) {
    int pk = ebuf[j];
    int rel = pk & 63, s = pk >> 6;
    int rr = rel - r0;
    if ((unsigned)rr < (unsigned)rc) {
      float coef = 1.0f / (float)cnt_nr[n * NRELS + rel];
      const float* row = big + (size_t)rr * NHTOT + (size_t)s * HID;
      a0 += coef * row[t];
      if (c1 < HID) a1 += coef * row[c1];
    }
  }
  int o0 = n * HID + t;
  if (!first) { a0 += hacc[o0]; if (c1 < HID) a1 += hacc[o0 + 64]; }
  if (!last) {
    hacc[o0] = a0; if (c1 < HID) hacc[o0 + 64] = a1;
  } else {
    float v0 = a0 + root1[o0] + bias1[t];
    h[o0] = v0 > 0.f ? v0 : 0.f;
    if (c1 < HID) {
      float v1 = a1 + root1[o0 + 64] + bias1[c1];
      h[o0 + 64] = v1 > 0.f ? v1 : 0.f;
    }
  }
}

// ---------------------------------------------------------------- Hx = h @ W2[r]  (chunked)
// tile: 80 nodes x 100 channels per block, one relation; 5x5 micro-tile, 320 threads
__global__ __launch_bounds__(320) void k_hx(const float* __restrict__ h,
                                            const float* __restrict__ W2,
                                            float* __restrict__ big, int r0) {
  __shared__ float hs[HID][81];   // [d][n], padded (81 ≡ 17 mod 32 -> conflict-free)
  __shared__ float wp[25][HID];   // one d-panel of W2[r]
  int r = r0 + blockIdx.y;
  int n0 = blockIdx.x * 80;
  int t = threadIdx.x;
  for (int idx = t; idx < 80 * HID; idx += 320) {
    int nn = idx / HID, d = idx - nn * HID;          // coalesced global read
    hs[d][nn] = h[(size_t)(n0 + nn) * HID + d];
  }
  int ng = t / 20, cg = t - ng * 20;  // 16 node-groups x 20 chan-groups
  int nb = ng * 5, cb = cg * 5;
  float acc[5][5] = {{0.f}};
  for (int p = 0; p < 4; ++p) {
    __syncthreads();
    for (int idx = t; idx < 25 * HID; idx += 320)
      wp[idx / HID][idx % HID] = W2[(size_t)r * HID * HID + p * 25 * HID + idx];
    __syncthreads();
    for (int dp = 0; dp < 25; ++dp) {
      int d = p * 25 + dp;
      float hv[5], wv[5];
#pragma unroll
      for (int i = 0; i < 5; ++i) hv[i] = hs[d][nb + i];
#pragma unroll
      for (int j = 0; j < 5; ++j) wv[j] = wp[dp][cb + j];
#pragma unroll
      for (int i = 0; i < 5; ++i)
#pragma unroll
        for (int j = 0; j < 5; ++j) acc[i][j] += hv[i] * wv[j];
    }
  }
  for (int i = 0; i < 5; ++i) {
    size_t o = (size_t)blockIdx.y * NHTOT + (size_t)(n0 + nb + i) * HID + cb;
#pragma unroll
    for (int j = 0; j < 5; ++j) big[o + j] = acc[i][j];
  }
}

// ---------------------------------------------------------------- conv2 aggregate + finalize
__global__ void k_agg2(const int* __restrict__ rowptr, const int* __restrict__ ebuf,
                       const int* __restrict__ cnt_nr, const float* __restrict__ big,
                       const float* __restrict__ h, const float* __restrict__ root2,
                       const float* __restrict__ bias2, float* __restrict__ acc2,
                       float* __restrict__ xout, int r0, int rc, int first, int last) {
  __shared__ float hl[HID];
  int n = blockIdx.x, t = threadIdx.x;
  int c1 = t + 64;
  float a0 = 0.f, a1 = 0.f;
  int beg = rowptr[n], end = rowptr[n + 1];
  for (int j = beg; j < end; ++j) {
    int pk = ebuf[j];
    int rel = pk & 63, s = pk >> 6;
    int rr = rel - r0;
    if ((unsigned)rr < (unsigned)rc) {
      float coef = 1.0f / (float)cnt_nr[n * NRELS + rel];
      const float* row = big + (size_t)rr * NHTOT + (size_t)s * HID;
      a0 += coef * row[t];
      if (c1 < HID) a1 += coef * row[c1];
    }
  }
  int o0 = n * HID + t;
  if (!first) { a0 += acc2[o0]; if (c1 < HID) a1 += acc2[o0 + 64]; }
  if (!last) {
    acc2[o0] = a0; if (c1 < HID) acc2[o0 + 64] = a1;
  } else {
    hl[t] = h[o0];
    if (c1 < HID) hl[c1] = h[o0 + 64];
    __syncthreads();
    float m0 = 0.f, m1 = 0.f;
    for (int d = 0; d < HID; ++d) {
      float hd = hl[d];
      m0 += hd * root2[d * HID + t];
      if (c1 < HID) m1 += hd * root2[d * HID + c1];
    }
    xout[o0] = a0 + m0 + bias2[t];
    if (c1 < HID) xout[o0 + 64] = a1 + m1 + bias2[c1];
  }
}

// ---------------------------------------------------------------- rel_embedded
__global__ void k_emb(const float4* __restrict__ emb, const int* __restrict__ et,
                      float4* __restrict__ out2) {
  int i = blockIdx.x * 256 + threadIdx.x;
  if (i >= E_EDGES * 25) return;
  int e = i / 25, q = i - e * 25;
  int r = et[e];
  float4 v;
  if (r == 0) { v.x = 0.f; v.y = 0.f; v.z = 0.f; v.w = 0.f; }
  else v = emb[r * 25 + q];
  out2[i] = v;
}

// ---------------------------------------------------------------- launch
extern "C" void kernel_launch(void* const* d_in, const int* in_sizes, int n_in,
                              void* d_out, int out_size, void* d_ws, size_t ws_size,
                              hipStream_t stream) {
  (void)in_sizes; (void)n_in; (void)out_size; (void)d_ws; (void)ws_size;

  const float* comp1  = (const float*)d_in[0];
  const float* basis1 = (const float*)d_in[1];
  const float* root1  = (const float*)d_in[2];
  const float* bias1  = (const float*)d_in[3];
  const float* comp2  = (const float*)d_in[4];
  const float* basis2 = (const float*)d_in[5];
  const float* root2  = (const float*)d_in[6];
  const float* bias2  = (const float*)d_in[7];
  const float* emb    = (const float*)d_in[8];
  const int*   ei     = (const int*)d_in[9];
  const int*   et     = (const int*)d_in[10];
  const int* srcp = ei;
  const int* dstp = ei + E_EDGES;

  float* xout = (float*)d_out;
  // scratch: the rel_embedded region (32M floats) — overwritten by k_emb at the end
  float* scratch = xout + NHTOT;
  int*   cnt_nr = (int*)scratch;            // 400,000
  int*   deg    = cnt_nr + 400000;          // 10,000
  int*   rowptr = deg + 10000;              // 10,001 (+3 pad)
  int*   fill   = rowptr + 10004;           // 10,000
  int*   ebuf   = fill + 10000;             // 320,000
  float* W2     = (float*)(ebuf + 320000);  // 400,000
  float* h      = W2 + 400000;              // 1,000,000
  float* hacc   = h + NHTOT;                // 1,000,000 (reused as acc2)
  float* big    = hacc + NHTOT;             // 20,000,000 (chunked W1 / Hx)
  // total = 23,150,004 floats < 32,000,000 available

  hipMemsetAsync(cnt_nr, 0, (size_t)(400000 + 10000 + 10004 + 10000) * sizeof(int), stream);

  k_count <<<(E_EDGES + 255) / 256, 256, 0, stream>>>(dstp, et, cnt_nr, deg);
  k_scan  <<<1, 256, 0, stream>>>(deg, rowptr);
  k_bucket<<<(E_EDGES + 255) / 256, 256, 0, stream>>>(srcp, dstp, et, rowptr, fill, ebuf);
  k_w2    <<<(HID * HID + 255) / 256, 256, 0, stream>>>(comp2, basis2, W2);

  const int RC = 20;
  for (int r0 = 0; r0 < NRELS; r0 += RC) {
    int rc = (NRELS - r0 < RC) ? (NRELS - r0) : RC;
    int first = (r0 == 0), last = (r0 + rc >= NRELS);
    k_w1  <<<(NHTOT + 255) / 256, 256, 0, stream>>>(comp1, basis1, big, r0, rc);
    k_agg1<<<NN, 64, 0, stream>>>(rowptr, ebuf, cnt_nr, big, root1, bias1, hacc, h,
                                  r0, rc, first, last);
  }
  for (int r0 = 0; r0 < NRELS; r0 += RC) {
    int rc = (NRELS - r0 < RC) ? (NRELS - r0) : RC;
    int first = (r0 == 0), last = (r0 + rc >= NRELS);
    k_hx  <<<dim3(NN / 80, rc), 320, 0, stream>>>(h, W2, big, r0);
    k_agg2<<<NN, 64, 0, stream>>>(rowptr, ebuf, cnt_nr, big, h, root2, bias2, hacc, xout,
                                  r0, rc, first, last);
  }
  k_emb<<<(E_EDGES * 25 + 255) / 256, 256, 0, stream>>>((const float4*)emb, et,
                                                        (float4*)(xout + NHTOT));
}

// Round 2
// 462.423 us; speedup vs baseline: 1.3824x; 1.3824x over previous
//
#include <hip/hip_runtime.h>
#include <hip/hip_bf16.h>
#include <cstdint>
#include <cstddef>

#define E_EDGES 320000
#define NN 10000
#define NRELS 40
#define NB 30
#define HID 100
#define NHTOT (NN*HID)       // 1,000,000
#define R2 41                // 40 rels + root2 slot
#define KPAD 128             // padded K per relation block
#define ASTRIDE (R2*KPAD)    // 5248 bf16 per hbar row
#define NROWS_PAD 10048      // 157 blocks * 64 rows

typedef short bf16x8 __attribute__((ext_vector_type(8)));
typedef float f32x4 __attribute__((ext_vector_type(4)));

__device__ inline ushort f2bf(float f) {
  uint x = __float_as_uint(f);
  return (ushort)((x + 0x7fffu + ((x >> 16) & 1u)) >> 16);
}
__device__ inline float bflo(uint u) { return __uint_as_float(u << 16); }
__device__ inline float bfhi(uint u) { return __uint_as_float(u & 0xffff0000u); }

// ---------------------------------------------------------------- edge meta
__global__ void k_count(const int* __restrict__ dst, const int* __restrict__ et,
                        int* __restrict__ cnt_nr, int* __restrict__ deg) {
  int e = blockIdx.x * blockDim.x + threadIdx.x;
  if (e >= E_EDGES) return;
  int d = dst[e], r = et[e];
  atomicAdd(&cnt_nr[d * NRELS + r], 1);
  atomicAdd(&deg[d], 1);
}

__global__ void k_scan(const int* __restrict__ deg, int* __restrict__ rowptr) {
  __shared__ int ssum[256];
  int t = threadIdx.x;
  const int per = (NN + 255) / 256;
  int base = t * per;
  int s = 0;
  for (int k = 0; k < per; ++k) { int i = base + k; if (i < NN) s += deg[i]; }
  ssum[t] = s; __syncthreads();
  for (int off = 1; off < 256; off <<= 1) {
    int v = (t >= off) ? ssum[t - off] : 0;
    __syncthreads();
    ssum[t] += v;
    __syncthreads();
  }
  int pre = (t == 0) ? 0 : ssum[t - 1];
  for (int k = 0; k < per; ++k) {
    int i = base + k;
    if (i < NN) { rowptr[i] = pre; pre += deg[i]; }
  }
  if (t == 255) rowptr[NN] = ssum[255];
}

__global__ void k_bucket(const int* __restrict__ src, const int* __restrict__ dst,
                         const int* __restrict__ et, const int* __restrict__ rowptr,
                         int* __restrict__ fill, int* __restrict__ ebuf) {
  int e = blockIdx.x * blockDim.x + threadIdx.x;
  if (e >= E_EDGES) return;
  int d = dst[e];
  int pos = rowptr[d] + atomicAdd(&fill[d], 1);
  ebuf[pos] = (src[e] << 6) | et[e];
}

// ---------------------------------------------------------------- W1 (bf16, all 40 rels, one pass)
__global__ void k_w1b(const float* __restrict__ comp1, const float* __restrict__ basis1,
                      uint* __restrict__ W1bf) {   // W1bf: [40][NHTOT/2] uints (2 bf16)
  int i2 = blockIdx.x * 256 + threadIdx.x;
  if (i2 >= NHTOT / 2) return;
  float2 v[NB];
#pragma unroll
  for (int b = 0; b < NB; ++b)
    v[b] = ((const float2*)basis1)[(size_t)b * (NHTOT / 2) + i2];
  for (int r = 0; r < NRELS; ++r) {
    float ax = 0.f, ay = 0.f;
#pragma unroll
    for (int b = 0; b < NB; ++b) {
      float c = comp1[r * NB + b];
      ax += c * v[b].x; ay += c * v[b].y;
    }
    W1bf[(size_t)r * (NHTOT / 2) + i2] = (uint)f2bf(ax) | ((uint)f2bf(ay) << 16);
  }
}

// ---------------------------------------------------------------- W2 fp32 then Bt bf16
__global__ void k_w2(const float* __restrict__ comp2, const float* __restrict__ basis2,
                     float* __restrict__ W2f) {
  int i = blockIdx.x * 256 + threadIdx.x;
  if (i >= HID * HID) return;
  float v[NB];
#pragma unroll
  for (int b = 0; b < NB; ++b) v[b] = basis2[b * HID * HID + i];
  for (int r = 0; r < NRELS; ++r) {
    float a = 0.f;
#pragma unroll
    for (int b = 0; b < NB; ++b) a += comp2[r * NB + b] * v[b];
    W2f[r * HID * HID + i] = a;
  }
}

// Bt[r][col][k] = (r<40 ? W2f[r][k][col] : root2[k][col]), zero-padded to 112x128
__global__ void k_bt(const float* __restrict__ W2f, const float* __restrict__ root2,
                     ushort* __restrict__ Bt) {
  int i = blockIdx.x * 256 + threadIdx.x;
  if (i >= R2 * 112 * KPAD) return;
  int k = i & (KPAD - 1);
  int rc = i >> 7;
  int col = rc % 112;
  int r = rc / 112;
  float v = 0.f;
  if (k < HID && col < HID)
    v = (r < NRELS) ? W2f[(r * HID + k) * HID + col] : root2[k * HID + col];
  Bt[i] = f2bf(v);
}

// ---------------------------------------------------------------- conv1 aggregate (bf16 W1 gather)
__global__ void k_agg1(const int* __restrict__ rowptr, const int* __restrict__ ebuf,
                       const int* __restrict__ cnt_nr, const uint* __restrict__ W1bf,
                       const float* __restrict__ root1, const float* __restrict__ bias1,
                       float* __restrict__ h) {
  int n = blockIdx.x, t = threadIdx.x;
  if (t >= 50) return;
  float a0 = 0.f, a1 = 0.f;
  int beg = rowptr[n], end = rowptr[n + 1];
  int j = beg;
  for (; j + 1 < end; j += 2) {
    int pk0 = ebuf[j], pk1 = ebuf[j + 1];
    int r0 = pk0 & 63, s0 = pk0 >> 6;
    int r1 = pk1 & 63, s1 = pk1 >> 6;
    float c0 = 1.0f / (float)cnt_nr[n * NRELS + r0];
    float c1 = 1.0f / (float)cnt_nr[n * NRELS + r1];
    uint u0 = W1bf[(size_t)(r0 * NN + s0) * 50 + t];
    uint u1 = W1bf[(size_t)(r1 * NN + s1) * 50 + t];
    a0 += c0 * bflo(u0) + c1 * bflo(u1);
    a1 += c0 * bfhi(u0) + c1 * bfhi(u1);
  }
  if (j < end) {
    int pk = ebuf[j];
    int r = pk & 63, s = pk >> 6;
    float c = 1.0f / (float)cnt_nr[n * NRELS + r];
    uint u = W1bf[(size_t)(r * NN + s) * 50 + t];
    a0 += c * bflo(u);
    a1 += c * bfhi(u);
  }
  int c0 = 2 * t, c1 = 2 * t + 1;
  float v0 = a0 + root1[n * HID + c0] + bias1[c0];
  float v1 = a1 + root1[n * HID + c1] + bias1[c1];
  h[n * HID + c0] = v0 > 0.f ? v0 : 0.f;
  h[n * HID + c1] = v1 > 0.f ? v1 : 0.f;
}

// ---------------------------------------------------------------- conv2 pre-aggregate: hbar (bf16)
__global__ __launch_bounds__(128) void k_hbar(const int* __restrict__ rowptr,
                                              const int* __restrict__ ebuf,
                                              const int* __restrict__ cnt_nr,
                                              const float* __restrict__ h,
                                              uint* __restrict__ hbar) { // [NROWS_PAD][ASTRIDE/2]
  __shared__ float acc[NRELS][HID];   // 16 KB
  int n = blockIdx.x, t = threadIdx.x;
  for (int i = t; i < NRELS * HID; i += 128) ((float*)acc)[i] = 0.f;
  __syncthreads();
  if (t < HID) {
    int beg = rowptr[n], end = rowptr[n + 1];
    int j = beg;
    for (; j + 1 < end; j += 2) {
      int pk0 = ebuf[j], pk1 = ebuf[j + 1];
      int r0 = pk0 & 63, s0 = pk0 >> 6;
      int r1 = pk1 & 63, s1 = pk1 >> 6;
      float h0 = h[s0 * HID + t];
      float h1 = h[s1 * HID + t];
      acc[r0][t] += h0;
      acc[r1][t] += h1;
    }
    if (j < end) {
      int pk = ebuf[j];
      acc[pk & 63][t] += h[(pk >> 6) * HID + t];
    }
  }
  __syncthreads();
  uint* orow = hbar + (size_t)n * (ASTRIDE / 2);
  for (int i = t; i < R2 * (KPAD / 2); i += 128) {
    int r = i >> 6;              // KPAD/2 = 64 uints per rel
    int kk = (i & 63) * 2;
    float v0 = 0.f, v1 = 0.f;
    if (kk < HID) {
      if (r < NRELS) {
        int c = cnt_nr[n * NRELS + r];
        float coef = c ? 1.0f / (float)c : 0.f;
        v0 = acc[r][kk] * coef;
        v1 = (kk + 1 < HID) ? acc[r][kk + 1] * coef : 0.f;
      } else {
        v0 = h[n * HID + kk];
        v1 = (kk + 1 < HID) ? h[n * HID + kk + 1] : 0.f;
      }
    }
    orow[i] = (uint)f2bf(v0) | ((uint)f2bf(v1) << 16);
  }
}

// ---------------------------------------------------------------- batched MFMA GEMM
// xout[n, c] = sum_{r<41} hbar[n, r, :] . Bt[r][c][:] + bias2[c]
__global__ __launch_bounds__(256) void k_gemm(const ushort* __restrict__ hbar,
                                              const ushort* __restrict__ Bt,
                                              const float* __restrict__ bias2,
                                              float* __restrict__ xout) {
  int t = threadIdx.x;
  int wid = t >> 6, l = t & 63;
  int lrow = l & 15, lk = (l >> 4) * 8;
  int n_base = blockIdx.x * 64 + wid * 16 + lrow;   // A-fragment row
  f32x4 acc[7];
#pragma unroll
  for (int j = 0; j < 7; ++j) acc[j] = (f32x4){0.f, 0.f, 0.f, 0.f};
  const ushort* ap = hbar + (size_t)n_base * ASTRIDE + lk;
  const ushort* bp = Bt + (size_t)lrow * KPAD + lk;
  for (int r = 0; r < R2; ++r) {
#pragma unroll
    for (int kb = 0; kb < 4; ++kb) {
      bf16x8 a = *(const bf16x8*)(ap + kb * 32);
#pragma unroll
      for (int j = 0; j < 7; ++j) {
        bf16x8 b = *(const bf16x8*)(bp + (size_t)j * 16 * KPAD + kb * 32);
        acc[j] = __builtin_amdgcn_mfma_f32_16x16x32_bf16(a, b, acc[j], 0, 0, 0);
      }
    }
    ap += KPAD;
    bp += 112 * KPAD;
  }
  int srow = blockIdx.x * 64 + wid * 16 + (l >> 4) * 4;  // C/D row base
#pragma unroll
  for (int j = 0; j < 7; ++j) {
    int col = j * 16 + lrow;
    if (col < HID) {
      float bb = bias2[col];
#pragma unroll
      for (int v = 0; v < 4; ++v) {
        int rr = srow + v;
        if (rr < NN) xout[(size_t)rr * HID + col] = acc[j][v] + bb;
      }
    }
  }
}

// ---------------------------------------------------------------- rel_embedded
__global__ void k_emb(const float4* __restrict__ emb, const int* __restrict__ et,
                      float4* __restrict__ out2) {
  int i = blockIdx.x * 256 + threadIdx.x;
  if (i >= E_EDGES * 25) return;
  int e = i / 25, q = i - e * 25;
  int r = et[e];
  float4 v;
  if (r == 0) { v.x = 0.f; v.y = 0.f; v.z = 0.f; v.w = 0.f; }
  else v = emb[r * 25 + q];
  out2[i] = v;
}

// ---------------------------------------------------------------- launch
extern "C" void kernel_launch(void* const* d_in, const int* in_sizes, int n_in,
                              void* d_out, int out_size, void* d_ws, size_t ws_size,
                              hipStream_t stream) {
  (void)in_sizes; (void)n_in; (void)out_size; (void)d_ws; (void)ws_size;

  const float* comp1  = (const float*)d_in[0];
  const float* basis1 = (const float*)d_in[1];
  const float* root1  = (const float*)d_in[2];
  const float* bias1  = (const float*)d_in[3];
  const float* comp2  = (const float*)d_in[4];
  const float* basis2 = (const float*)d_in[5];
  const float* root2  = (const float*)d_in[6];
  const float* bias2  = (const float*)d_in[7];
  const float* emb    = (const float*)d_in[8];
  const int*   ei     = (const int*)d_in[9];
  const int*   et     = (const int*)d_in[10];
  const int* srcp = ei;
  const int* dstp = ei + E_EDGES;

  float* xout = (float*)d_out;
  float* scratch = xout + NHTOT;            // 32M floats (overwritten by k_emb last)
  int*   cnt_nr = (int*)scratch;            // 400,000
  int*   deg    = cnt_nr + 400000;          // 10,000
  int*   rowptr = deg + 10000;              // 10,004
  int*   fill   = rowptr + 10004;           // 10,000
  int*   ebuf   = fill + 10000;             // 320,000  -> ints end at 750,004
  float* W2f    = scratch + 750016;         // 400,000
  ushort* Bt    = (ushort*)(scratch + 1150016);  // 587,776 bf16 = 293,888 floats
  float* h      = scratch + 1443904;        // 1,000,000
  uint*  W1bf   = (uint*)(scratch + 2443904);    // conv1: 40*500,000 uints = 20M floats
  uint*  hbar   = (uint*)(scratch + 2443904);    // conv2: NROWS_PAD*2624 uints = 26.37M floats
  // big region end: 2,443,904 + 26,365,952 = 28,809,856 < 32,000,000  OK

  hipMemsetAsync(cnt_nr, 0, (size_t)430004 * sizeof(int), stream);
  // zero the 48 pad rows of hbar (rows 10000..10047) so GEMM tail reads zeros
  hipMemsetAsync((char*)hbar + (size_t)NN * ASTRIDE * 2, 0,
                 (size_t)(NROWS_PAD - NN) * ASTRIDE * 2, stream);

  k_count <<<(E_EDGES + 255) / 256, 256, 0, stream>>>(dstp, et, cnt_nr, deg);
  k_scan  <<<1, 256, 0, stream>>>(deg, rowptr);
  k_bucket<<<(E_EDGES + 255) / 256, 256, 0, stream>>>(srcp, dstp, et, rowptr, fill, ebuf);

  k_w2 <<<(HID * HID + 255) / 256, 256, 0, stream>>>(comp2, basis2, W2f);
  k_bt <<<(R2 * 112 * KPAD + 255) / 256, 256, 0, stream>>>(W2f, root2, Bt);
  k_w1b<<<(NHTOT / 2 + 255) / 256, 256, 0, stream>>>(comp1, basis1, W1bf);

  k_agg1<<<NN, 64, 0, stream>>>(rowptr, ebuf, cnt_nr, W1bf, root1, bias1, h);
  k_hbar<<<NN, 128, 0, stream>>>(rowptr, ebuf, cnt_nr, h, hbar);
  k_gemm<<<(NN + 63) / 64, 256, 0, stream>>>((const ushort*)hbar, Bt, bias2, xout);

  k_emb<<<(E_EDGES * 25 + 255) / 256, 256, 0, stream>>>((const float4*)emb, et,
                                                        (float4*)(xout + NHTOT));
}

// Round 3
// 367.525 us; speedup vs baseline: 1.7394x; 1.2582x over previous
//
#include <hip/hip_runtime.h>
#include <hip/hip_bf16.h>
#include <cstdint>
#include <cstddef>

#define E_EDGES 320000
#define NN 10000
#define NRELS 40
#define NB 30
#define HID 100
#define NHTOT (NN*HID)       // 1,000,000
#define R2 41                // 40 rels + root2 slot
#define KTOT 4224            // 41*100 = 4100 packed, padded to 33*128
#define NROWS_PAD 10048      // 157 blocks * 64 rows
#define SPLITK 6             // 132 kb-steps -> 22 per gy

typedef short bf16x8 __attribute__((ext_vector_type(8)));
typedef float f32x4 __attribute__((ext_vector_type(4)));

__device__ inline ushort f2bf(float f) {
  uint x = __float_as_uint(f);
  return (ushort)((x + 0x7fffu + ((x >> 16) & 1u)) >> 16);
}
__device__ inline float bflo(uint u) { return __uint_as_float(u << 16); }
__device__ inline float bfhi(uint u) { return __uint_as_float(u & 0xffff0000u); }

// ---------------------------------------------------------------- edge meta
__global__ void k_count(const int* __restrict__ dst, const int* __restrict__ et,
                        int* __restrict__ cnt_nr, int* __restrict__ deg) {
  int e = blockIdx.x * blockDim.x + threadIdx.x;
  if (e >= E_EDGES) return;
  int d = dst[e], r = et[e];
  atomicAdd(&cnt_nr[d * NRELS + r], 1);
  atomicAdd(&deg[d], 1);
}

__global__ void k_scan(const int* __restrict__ deg, int* __restrict__ rowptr) {
  __shared__ int ssum[256];
  int t = threadIdx.x;
  const int per = (NN + 255) / 256;
  int base = t * per;
  int s = 0;
  for (int k = 0; k < per; ++k) { int i = base + k; if (i < NN) s += deg[i]; }
  ssum[t] = s; __syncthreads();
  for (int off = 1; off < 256; off <<= 1) {
    int v = (t >= off) ? ssum[t - off] : 0;
    __syncthreads();
    ssum[t] += v;
    __syncthreads();
  }
  int pre = (t == 0) ? 0 : ssum[t - 1];
  for (int k = 0; k < per; ++k) {
    int i = base + k;
    if (i < NN) { rowptr[i] = pre; pre += deg[i]; }
  }
  if (t == 255) rowptr[NN] = ssum[255];
}

__global__ void k_bucket(const int* __restrict__ src, const int* __restrict__ dst,
                         const int* __restrict__ et, const int* __restrict__ rowptr,
                         int* __restrict__ fill, int* __restrict__ ebuf) {
  int e = blockIdx.x * blockDim.x + threadIdx.x;
  if (e >= E_EDGES) return;
  int d = dst[e];
  int pos = rowptr[d] + atomicAdd(&fill[d], 1);
  ebuf[pos] = (src[e] << 6) | et[e];
}

// ---------------------------------------------------------------- W1 (bf16, all 40 rels)
__global__ void k_w1b(const float* __restrict__ comp1, const float* __restrict__ basis1,
                      uint* __restrict__ W1bf) {   // [40][NHTOT/2] uints
  int i2 = blockIdx.x * 256 + threadIdx.x;
  if (i2 >= NHTOT / 2) return;
  float2 v[NB];
#pragma unroll
  for (int b = 0; b < NB; ++b)
    v[b] = ((const float2*)basis1)[(size_t)b * (NHTOT / 2) + i2];
  for (int r = 0; r < NRELS; ++r) {
    float ax = 0.f, ay = 0.f;
#pragma unroll
    for (int b = 0; b < NB; ++b) {
      float c = comp1[r * NB + b];
      ax += c * v[b].x; ay += c * v[b].y;
    }
    W1bf[(size_t)r * (NHTOT / 2) + i2] = (uint)f2bf(ax) | ((uint)f2bf(ay) << 16);
  }
}

// ---------------------------------------------------------------- W2 fp32 then packed Bt bf16
__global__ void k_w2(const float* __restrict__ comp2, const float* __restrict__ basis2,
                     float* __restrict__ W2f) {
  int i = blockIdx.x * 256 + threadIdx.x;
  if (i >= HID * HID) return;
  float v[NB];
#pragma unroll
  for (int b = 0; b < NB; ++b) v[b] = basis2[b * HID * HID + i];
  for (int r = 0; r < NRELS; ++r) {
    float a = 0.f;
#pragma unroll
    for (int b = 0; b < NB; ++b) a += comp2[r * NB + b] * v[b];
    W2f[r * HID * HID + i] = a;
  }
}

// Bt[col][kk] with packed K: kk = r*100 + k  (r<40: W2f[r][k][col], r==40: root2[k][col])
__global__ void k_bt(const float* __restrict__ W2f, const float* __restrict__ root2,
                     ushort* __restrict__ Bt) {
  int i = blockIdx.x * 256 + threadIdx.x;
  if (i >= 112 * KTOT) return;
  int col = i / KTOT, kk = i - col * KTOT;
  float v = 0.f;
  if (kk < R2 * HID && col < HID) {
    int r = kk / HID, k = kk - r * HID;
    v = (r < NRELS) ? W2f[(r * HID + k) * HID + col] : root2[k * HID + col];
  }
  Bt[i] = f2bf(v);
}

// ---------------------------------------------------------------- conv1 aggregate
__global__ void k_agg1(const int* __restrict__ rowptr, const int* __restrict__ ebuf,
                       const int* __restrict__ cnt_nr, const uint* __restrict__ W1bf,
                       const float* __restrict__ root1, const float* __restrict__ bias1,
                       float* __restrict__ h) {
  int n = blockIdx.x, t = threadIdx.x;
  if (t >= 50) return;
  float a0 = 0.f, a1 = 0.f;
  int beg = rowptr[n], end = rowptr[n + 1];
  int j = beg;
  for (; j + 1 < end; j += 2) {
    int pk0 = ebuf[j], pk1 = ebuf[j + 1];
    int r0 = pk0 & 63, s0 = pk0 >> 6;
    int r1 = pk1 & 63, s1 = pk1 >> 6;
    float c0 = 1.0f / (float)cnt_nr[n * NRELS + r0];
    float c1 = 1.0f / (float)cnt_nr[n * NRELS + r1];
    uint u0 = W1bf[(size_t)(r0 * NN + s0) * 50 + t];
    uint u1 = W1bf[(size_t)(r1 * NN + s1) * 50 + t];
    a0 += c0 * bflo(u0) + c1 * bflo(u1);
    a1 += c0 * bfhi(u0) + c1 * bfhi(u1);
  }
  if (j < end) {
    int pk = ebuf[j];
    int r = pk & 63, s = pk >> 6;
    float c = 1.0f / (float)cnt_nr[n * NRELS + r];
    uint u = W1bf[(size_t)(r * NN + s) * 50 + t];
    a0 += c * bflo(u);
    a1 += c * bfhi(u);
  }
  int c0 = 2 * t, c1 = 2 * t + 1;
  float v0 = a0 + root1[n * HID + c0] + bias1[c0];
  float v1 = a1 + root1[n * HID + c1] + bias1[c1];
  h[n * HID + c0] = v0 > 0.f ? v0 : 0.f;
  h[n * HID + c1] = v1 > 0.f ? v1 : 0.f;
}

// ---------------------------------------------------------------- hbar (packed bf16 rows)
__global__ __launch_bounds__(128) void k_hbar(const int* __restrict__ rowptr,
                                              const int* __restrict__ ebuf,
                                              const int* __restrict__ cnt_nr,
                                              const float* __restrict__ h,
                                              uint* __restrict__ hbar) { // [NROWS_PAD][KTOT/2]
  __shared__ float acc[NRELS][HID];   // 16 KB
  int n = blockIdx.x, t = threadIdx.x;
  for (int i = t; i < NRELS * HID; i += 128) ((float*)acc)[i] = 0.f;
  __syncthreads();
  if (t < HID) {
    int beg = rowptr[n], end = rowptr[n + 1];
    int j = beg;
    for (; j + 1 < end; j += 2) {
      int pk0 = ebuf[j], pk1 = ebuf[j + 1];
      int r0 = pk0 & 63, s0 = pk0 >> 6;
      int r1 = pk1 & 63, s1 = pk1 >> 6;
      float h0 = h[s0 * HID + t];
      float h1 = h[s1 * HID + t];
      acc[r0][t] += h0;
      acc[r1][t] += h1;
    }
    if (j < end) {
      int pk = ebuf[j];
      acc[pk & 63][t] += h[(pk >> 6) * HID + t];
    }
  }
  __syncthreads();
  uint* orow = hbar + (size_t)n * (KTOT / 2);
  for (int i = t; i < KTOT / 2; i += 128) {
    float v0 = 0.f, v1 = 0.f;
    if (i < R2 * 50) {
      int r = i / 50;
      int kk = (i - r * 50) * 2;
      if (r < NRELS) {
        int c = cnt_nr[n * NRELS + r];
        float coef = c ? 1.0f / (float)c : 0.f;
        v0 = acc[r][kk] * coef;
        v1 = acc[r][kk + 1] * coef;
      } else {
        v0 = h[n * HID + kk];
        v1 = h[n * HID + kk + 1];
      }
    }
    orow[i] = (uint)f2bf(v0) | ((uint)f2bf(v1) << 16);
  }
}

// ---------------------------------------------------------------- split-K MFMA GEMM
// part[gy][row][col] = hbar[row, kb0*32 : kb1*32] . Bt[col][same]
__global__ __launch_bounds__(256) void k_gemm(const ushort* __restrict__ hbar,
                                              const ushort* __restrict__ Bt,
                                              float* __restrict__ part) {
  int t = threadIdx.x;
  int wid = t >> 6, l = t & 63;
  int lrow = l & 15, lk = (l >> 4) * 8;
  int kb0 = blockIdx.y * (132 / SPLITK);
  int kb1 = kb0 + (132 / SPLITK);
  int n_base = blockIdx.x * 64 + wid * 16 + lrow;
  f32x4 acc[7];
#pragma unroll
  for (int j = 0; j < 7; ++j) acc[j] = (f32x4){0.f, 0.f, 0.f, 0.f};
  const ushort* ap = hbar + (size_t)n_base * KTOT + lk;
  const ushort* bp = Bt + (size_t)lrow * KTOT + lk;
  for (int kb = kb0; kb < kb1; ++kb) {
    bf16x8 a = *(const bf16x8*)(ap + kb * 32);
#pragma unroll
    for (int j = 0; j < 7; ++j) {
      bf16x8 b = *(const bf16x8*)(bp + (size_t)j * 16 * KTOT + kb * 32);
      acc[j] = __builtin_amdgcn_mfma_f32_16x16x32_bf16(a, b, acc[j], 0, 0, 0);
    }
  }
  float* pp = part + (size_t)blockIdx.y * NROWS_PAD * 112;
  int srow = blockIdx.x * 64 + wid * 16 + (l >> 4) * 4;
#pragma unroll
  for (int j = 0; j < 7; ++j) {
    int col = j * 16 + lrow;
#pragma unroll
    for (int v = 0; v < 4; ++v)
      pp[(size_t)(srow + v) * 112 + col] = acc[j][v];
  }
}

// reduce partials + bias
__global__ void k_red(const float* __restrict__ part, const float* __restrict__ bias2,
                      float* __restrict__ xout) {
  int i = blockIdx.x * 256 + threadIdx.x;
  if (i >= NHTOT) return;
  int n = i / HID, c = i - n * HID;
  float s = bias2[c];
#pragma unroll
  for (int g = 0; g < SPLITK; ++g)
    s += part[(size_t)g * NROWS_PAD * 112 + (size_t)n * 112 + c];
  xout[i] = s;
}

// ---------------------------------------------------------------- rel_embedded
__global__ void k_emb(const float4* __restrict__ emb, const int* __restrict__ et,
                      float4* __restrict__ out2) {
  int i = blockIdx.x * 256 + threadIdx.x;
  if (i >= E_EDGES * 25) return;
  int e = i / 25, q = i - e * 25;
  int r = et[e];
  float4 v;
  if (r == 0) { v.x = 0.f; v.y = 0.f; v.z = 0.f; v.w = 0.f; }
  else v = emb[r * 25 + q];
  out2[i] = v;
}

// ---------------------------------------------------------------- launch
extern "C" void kernel_launch(void* const* d_in, const int* in_sizes, int n_in,
                              void* d_out, int out_size, void* d_ws, size_t ws_size,
                              hipStream_t stream) {
  (void)in_sizes; (void)n_in; (void)out_size; (void)d_ws; (void)ws_size;

  const float* comp1  = (const float*)d_in[0];
  const float* basis1 = (const float*)d_in[1];
  const float* root1  = (const float*)d_in[2];
  const float* bias1  = (const float*)d_in[3];
  const float* comp2  = (const float*)d_in[4];
  const float* basis2 = (const float*)d_in[5];
  const float* root2  = (const float*)d_in[6];
  const float* bias2  = (const float*)d_in[7];
  const float* emb    = (const float*)d_in[8];
  const int*   ei     = (const int*)d_in[9];
  const int*   et     = (const int*)d_in[10];
  const int* srcp = ei;
  const int* dstp = ei + E_EDGES;

  float* xout = (float*)d_out;
  float* scratch = xout + NHTOT;            // 32M floats (overwritten by k_emb last)
  int*   cnt_nr = (int*)scratch;            // @0        400,000
  int*   deg    = cnt_nr + 400000;          // @400,000   10,000
  int*   rowptr = deg + 10000;              // @410,000   10,004
  int*   fill   = rowptr + 10004;           // @420,004   10,000
  int*   ebuf   = fill + 10000;             // @430,004  320,000 -> 750,004
  float* W2f    = scratch + 750016;         // 400,000 -> 1,150,016
  ushort* Bt    = (ushort*)(scratch + 1150016);  // 112*4224 bf16 = 236,544 f -> 1,386,560
  float* h      = scratch + 1386560;        // 1,000,000 -> 2,386,560
  uint*  W1bf   = (uint*)(scratch + 2386560);    // conv1 use: 20M floats
  uint*  hbar   = (uint*)(scratch + 2386560);    // conv2 use: 10048*2112 uints = 21.22M f
  float* part   = scratch + 23607936;       // 6*10048*112 = 6,752,256 -> 30,360,192 OK

  hipMemsetAsync(cnt_nr, 0, (size_t)430004 * sizeof(int), stream);
  // zero the 48 pad rows of hbar so GEMM tail reads zeros
  hipMemsetAsync((char*)hbar + (size_t)NN * KTOT * 2, 0,
                 (size_t)(NROWS_PAD - NN) * KTOT * 2, stream);

  k_count <<<(E_EDGES + 255) / 256, 256, 0, stream>>>(dstp, et, cnt_nr, deg);
  k_scan  <<<1, 256, 0, stream>>>(deg, rowptr);
  k_bucket<<<(E_EDGES + 255) / 256, 256, 0, stream>>>(srcp, dstp, et, rowptr, fill, ebuf);

  k_w2 <<<(HID * HID + 255) / 256, 256, 0, stream>>>(comp2, basis2, W2f);
  k_bt <<<(112 * KTOT + 255) / 256, 256, 0, stream>>>(W2f, root2, Bt);
  k_w1b<<<(NHTOT / 2 + 255) / 256, 256, 0, stream>>>(comp1, basis1, W1bf);

  k_agg1<<<NN, 64, 0, stream>>>(rowptr, ebuf, cnt_nr, W1bf, root1, bias1, h);
  k_hbar<<<NN, 128, 0, stream>>>(rowptr, ebuf, cnt_nr, h, hbar);
  k_gemm<<<dim3((NN + 63) / 64, SPLITK), 256, 0, stream>>>((const ushort*)hbar, Bt, part);
  k_red <<<(NHTOT + 255) / 256, 256, 0, stream>>>(part, bias2, xout);

  k_emb<<<(E_EDGES * 25 + 255) / 256, 256, 0, stream>>>((const float4*)emb, et,
                                                        (float4*)(xout + NHTOT));
}